// Round 9
// baseline (1004.862 us; speedup 1.0000x reference)
//
#include <hip/hip_runtime.h>

// Problem constants
#define B_SZ 512
#define T_SZ 512
#define I_SZ 256
#define H_SZ 250

typedef __bf16 bf16x8 __attribute__((ext_vector_type(8)));
typedef float  f32x4  __attribute__((ext_vector_type(4)));

__device__ __forceinline__ float fast_tanh(float x) {
    float ax = __builtin_fabsf(x);
    float e  = __expf(-2.0f * ax);          // v_exp_f32 path
    float r  = (1.0f - e) / (1.0f + e);
    return __builtin_copysignf(r, x);
}

// ---------------------------------------------------------------------------
// FUSED kernel: h_t = tanh(x_t @ Wx^T + h_{t-1} @ Wh^T + bh), out[b][t][:] = h_t
// One kernel, 256 blocks x 512 threads (8 waves), 2 batches per block.
// Why fused (round-8 counters): separate xproj GEMM measured ~390 µs and rnn
// was latency-bound at 28% MfmaUtil — the x-proj MFMAs are independent work
// that fills rnn's idle step cycles, and fusion deletes the 524 MB
// intermediate round-trip plus one dispatch.
//  - batches at A-rows 0/4 -> C rows 0 (quad0,r0) and 4 (quad1,r0)
//  - j-split 8 ways: wave owns 32 cols (2 n-tiles); Wh AND Wx B-frags in
//    registers (wfh[2][8] + wfx[2][8] = 128 VGPR)
//  - h ping-pong + x staging ping-pong in LDS, kt-interleaved CONFLICT-FREE
//    layout (measured 0 bank conflicts): elem = kt*96 + sel*32 + quad*8 + e;
//    sel 0 = batch0 (lane l15==0), 1 = batch1 (l15==4), 2 = zero (broadcast)
//  - x_t+1 loaded at step top (1 float/thread, coalesced), vmcnt-waited at
//    step bottom (~1 step ≈ 1300 cyc > 900 cyc HBM latency -> ~free),
//    ds_written to xbuf[nxt] under the same barrier as h
//  - MFMA chains seeded with zero-C operand (no per-step acc zeroing);
//    4 chains/wave (cx[2], ch[2]) x 8 waves = plenty of ILP for the pipe
//  - step barrier = s_waitcnt lgkmcnt(0) + raw s_barrier (never vmcnt(0):
//    out stores stay in flight across steps)
// Per-CU MFMA floor: 8 waves x 32 MFMA x 4.85 cyc = 1242 cyc/step.
// ---------------------------------------------------------------------------
__global__ __launch_bounds__(512, 2) void rnn_fused(
    const float* __restrict__ x,    // [B][T][256]
    const float* __restrict__ h0,   // [B][250]
    const float* __restrict__ Wx,   // [250][256]
    const float* __restrict__ Wh,   // [250][250]
    const float* __restrict__ bh,   // [250]
    float* __restrict__ out)        // [B][T][250]
{
    __shared__ __align__(16) __bf16 hbuf[2][768];   // h state ping-pong
    __shared__ __align__(16) __bf16 xbuf[2][768];   // x_t staging ping-pong

    const int b0   = blockIdx.x * 2;
    const int tid  = threadIdx.x;
    const int lane = tid & 63;
    const int wave = tid >> 6;       // 0..7
    const int l15  = lane & 15;
    const int quad = lane >> 4;      // 0..3
    const int j0w  = wave * 32;      // 32 cols per wave

    // zero all buffers (zero slots + k>=250 padding of h stay 0 forever)
    for (int i = tid; i < 2 * 768; i += 512) {
        ((__bf16*)hbuf)[i] = (__bf16)0.f;
        ((__bf16*)xbuf)[i] = (__bf16)0.f;
    }

    // init h into buf0: batch0 -> sel 0, batch1 -> sel 1
    // k -> elem: (k>>5)*96 + sel*32 + ((k>>3)&3)*8 + (k&7)
    for (int k = tid; k < H_SZ; k += 512) {
        int e = ((k >> 5) * 96) + (((k >> 3) & 3) << 3) + (k & 7);
        hbuf[0][e +  0] = (__bf16)h0[(size_t)(b0 + 0) * H_SZ + k];
        hbuf[0][e + 32] = (__bf16)h0[(size_t)(b0 + 1) * H_SZ + k];
    }

    // x staging geometry: thread -> (sel = batch, k); stage x(t=0) now
    const int xsel = tid >> 8;          // waves 0-3 -> batch0, 4-7 -> batch1
    const int xk   = tid & 255;
    const int xe   = ((xk >> 5) * 96) + xsel * 32 + (((xk >> 3) & 3) << 3) + (xk & 7);
    const float* xg = x + (size_t)(b0 + xsel) * T_SZ * I_SZ + xk;   // t = 0
    xbuf[0][xe] = (__bf16)xg[0];
    xg += I_SZ;                          // now points at t = 1

    // B-fragments in registers: wfh (Wh), wfx (Wx)
    // B[k = quad*8+e][n = l15]; n = j0w + tl*16 + l15, k = kt*32 + quad*8 + e
    bf16x8 wfh[2][8], wfx[2][8];
    float  bhv[2];
#pragma unroll
    for (int tl = 0; tl < 2; ++tl) {
        const int  j  = j0w + tl * 16 + l15;
        const bool jv = (j < H_SZ);
        bhv[tl] = jv ? bh[j] : 0.f;
#pragma unroll
        for (int kt = 0; kt < 8; ++kt) {
            const int kb = kt * 32 + quad * 8;
            bf16x8 vh, vx;
#pragma unroll
            for (int e = 0; e < 8; ++e) {
                const int k = kb + e;
                vh[e] = (jv && k < H_SZ) ? (__bf16)Wh[(size_t)j * H_SZ + k] : (__bf16)0.f;
                vx[e] = jv               ? (__bf16)Wx[(size_t)j * I_SZ + k] : (__bf16)0.f;
            }
            wfh[tl][kt] = vh;
            wfx[tl][kt] = vx;
        }
    }
    __syncthreads();

    // A-frag row source: l15==0 -> batch0 slot, l15==4 -> batch1, else zero
    const int aoff = (l15 == 0) ? 0 : ((l15 == 4) ? 32 : 64);
    const int qa   = quad & 1;           // batch select for epilogue quads 0/1

    bool   act[2];
    int    we[2];
    float* outp[2];
#pragma unroll
    for (int tl = 0; tl < 2; ++tl) {
        const int j = j0w + tl * 16 + l15;
        act[tl] = (quad < 2) && (j < H_SZ);
        const int jc = (j < H_SZ) ? j : 0;           // keep addr in-range
        we[tl]  = ((jc >> 5) * 96) + qa * 32 + (((jc >> 3) & 3) << 3) + (jc & 7);
        outp[tl] = out + (size_t)(b0 + qa) * T_SZ * H_SZ + jc;
    }

    const f32x4 vzero = (f32x4){0.f, 0.f, 0.f, 0.f};

    auto step = [&](int t, int cur, int nxt) {
        // issue x(t+1) load (1 float/thread, coalesced; in flight all step)
        const bool pf = (t + 1 < T_SZ);
        float xv = 0.f;
        if (pf) xv = xg[0];

        // ---- x-projection: independent of this step's h, fills latency
        bf16x8 axf[8];
#pragma unroll
        for (int kt = 0; kt < 8; ++kt)
            axf[kt] = *(const bf16x8*)&xbuf[cur][kt * 96 + aoff + quad * 8];
        f32x4 cx[2], ch[2];
#pragma unroll
        for (int tl = 0; tl < 2; ++tl)
            cx[tl] = __builtin_amdgcn_mfma_f32_16x16x32_bf16(axf[0], wfx[tl][0], vzero, 0, 0, 0);
#pragma unroll
        for (int kt = 1; kt < 8; ++kt)
#pragma unroll
            for (int tl = 0; tl < 2; ++tl)
                cx[tl] = __builtin_amdgcn_mfma_f32_16x16x32_bf16(axf[kt], wfx[tl][kt], cx[tl], 0, 0, 0);

        // ---- recurrence
        bf16x8 ahf[8];
#pragma unroll
        for (int kt = 0; kt < 8; ++kt)
            ahf[kt] = *(const bf16x8*)&hbuf[cur][kt * 96 + aoff + quad * 8];
#pragma unroll
        for (int tl = 0; tl < 2; ++tl)
            ch[tl] = __builtin_amdgcn_mfma_f32_16x16x32_bf16(ahf[0], wfh[tl][0], vzero, 0, 0, 0);
#pragma unroll
        for (int kt = 1; kt < 8; ++kt)
#pragma unroll
            for (int tl = 0; tl < 2; ++tl)
                ch[tl] = __builtin_amdgcn_mfma_f32_16x16x32_bf16(ahf[kt], wfh[tl][kt], ch[tl], 0, 0, 0);

        // ---- epilogue: C row (m) = quad*4 + r, col (n) = lane&15
        // batch0 -> row 0 (quad0,r0), batch1 -> row 4 (quad1,r0)
#pragma unroll
        for (int tl = 0; tl < 2; ++tl) {
            const float v = fast_tanh(cx[tl][0] + ch[tl][0] + bhv[tl]);
            if (act[tl]) {
                hbuf[nxt][we[tl]] = (__bf16)v;   // h for next step (LDS first)
                outp[tl][0] = v;                 // fire-and-forget global store
            }
            outp[tl] += H_SZ;
        }

        // ---- stage x(t+1): vmcnt wait happens here (counted, covers ~1 step)
        if (pf) xbuf[nxt][xe] = (__bf16)xv;
        xg += I_SZ;

        // end-of-step sync: LDS drained; NO vmcnt drain (stores in flight)
        asm volatile("s_waitcnt lgkmcnt(0)" ::: "memory");
        __builtin_amdgcn_s_barrier();
        asm volatile("" ::: "memory");
    };

    for (int t = 0; t < T_SZ; t += 2) {
        step(t,     0, 1);
        step(t + 1, 1, 0);
    }
}

extern "C" void kernel_launch(void* const* d_in, const int* in_sizes, int n_in,
                              void* d_out, int out_size, void* d_ws, size_t ws_size,
                              hipStream_t stream) {
    const float* x  = (const float*)d_in[0];
    const float* h  = (const float*)d_in[1];
    const float* Wx = (const float*)d_in[2];
    const float* Wh = (const float*)d_in[3];
    const float* bh = (const float*)d_in[4];
    float* out = (float*)d_out;

    rnn_fused<<<dim3(B_SZ / 2), dim3(512), 0, stream>>>(x, h, Wx, Wh, bh, out);
}